// Round 1
// 505.811 us; speedup vs baseline: 1.0526x; 1.0526x over previous
//
#include <hip/hip_runtime.h>
#include <math.h>

#define NEG 0.01f

typedef _Float16 f16;
typedef f16 h2 __attribute__((ext_vector_type(2)));

__device__ __forceinline__ float lrelu(float x) { return x > 0.f ? x : NEG * x; }

__device__ __forceinline__ h2 lrelu2(h2 x) {
    h2 y = x * (f16)0.01f;                        // v_pk_mul_f16
    return __builtin_elementwise_max(x, y);       // v_pk_max_f16 (x<0 -> 0.01x)
}

// sum across each 16-lane row via DPP; result in all 16 lanes of the row
__device__ __forceinline__ float q16_allsum(float v) {
    int x;
    x = __builtin_amdgcn_update_dpp(0, __float_as_int(v), 0xB1, 0xF, 0xF, true);  v += __int_as_float(x); // quad_perm xor1
    x = __builtin_amdgcn_update_dpp(0, __float_as_int(v), 0x4E, 0xF, 0xF, true);  v += __int_as_float(x); // quad_perm xor2
    x = __builtin_amdgcn_update_dpp(0, __float_as_int(v), 0x124, 0xF, 0xF, true); v += __int_as_float(x); // row_ror:4
    x = __builtin_amdgcn_update_dpp(0, __float_as_int(v), 0x128, 0xF, 0xF, true); v += __int_as_float(x); // row_ror:8
    return v;
}

__device__ __forceinline__ float x16_32_sum(float v) {
    v += __int_as_float(__builtin_amdgcn_ds_swizzle(__float_as_int(v), 0x401F)); // xor 16
    v += __shfl_xor(v, 32, 64);
    return v;
}

// ---------------- CSR build ----------------
// k_zero also packs the per-layer conv weights (fp16 ConvW layout) into ws:
// slot i in [0,48): layer l=i>>4, lane-slot t=i&15; 5 x uint4 per slot.
__global__ void k_zero(int* __restrict__ deg, int n,
                       const float* __restrict__ lin1, const float* __restrict__ attl,
                       uint4* __restrict__ wpack) {
    int i = blockIdx.x * blockDim.x + threadIdx.x;
    if (i < n) deg[i] = 0;
    if (i < 48) {
        int l = i >> 4, t = i & 15;
        const float* wb  = lin1 + (size_t)l * 71 * 64 + 64 * 64;  // rows 64..70
        const float* alp = attl + l * 64;
        unsigned int u[20];
#pragma unroll
        for (int j = 0; j < 4; j++) {
            int f = 4 * t + j;
            h2 a = { (f16)wb[f],       (f16)wb[64 + f]  }; u[j]      = __builtin_bit_cast(unsigned int, a);
            h2 b = { (f16)wb[128 + f], (f16)wb[192 + f] }; u[4 + j]  = __builtin_bit_cast(unsigned int, b);
            h2 c = { (f16)wb[256 + f], (f16)wb[320 + f] }; u[8 + j]  = __builtin_bit_cast(unsigned int, c);
            h2 d = { (f16)wb[384 + f], (f16)0.f         }; u[12 + j] = __builtin_bit_cast(unsigned int, d);
        }
        h2 e0 = { (f16)alp[4 * t],     (f16)alp[4 * t + 1] }; u[16] = __builtin_bit_cast(unsigned int, e0);
        h2 e1 = { (f16)alp[4 * t + 2], (f16)alp[4 * t + 3] }; u[17] = __builtin_bit_cast(unsigned int, e1);
        u[18] = 0; u[19] = 0;
        uint4* o = wpack + (size_t)i * 5;
        o[0] = make_uint4(u[0],  u[1],  u[2],  u[3]);
        o[1] = make_uint4(u[4],  u[5],  u[6],  u[7]);
        o[2] = make_uint4(u[8],  u[9],  u[10], u[11]);
        o[3] = make_uint4(u[12], u[13], u[14], u[15]);
        o[4] = make_uint4(u[16], u[17], u[18], u[19]);
    }
}

__global__ void k_count(const int* __restrict__ dst, int* __restrict__ deg,
                        int* __restrict__ rank, int E) {
    int e = blockIdx.x * blockDim.x + threadIdx.x;
    if (e < E) rank[e] = atomicAdd(&deg[dst[e]], 1);
}

__global__ __launch_bounds__(256) void k_scan_part(const int* __restrict__ deg,
                                                   int* __restrict__ bsum, int n) {
    __shared__ int sh[256];
    int b = blockIdx.x, t = threadIdx.x;
    int i0 = b * 1024 + t * 4;
    int s = 0;
    if (i0 + 3 < n) { int4 v = *(const int4*)(deg + i0); s = v.x + v.y + v.z + v.w; }
    else { for (int k = 0; k < 4; k++) if (i0 + k < n) s += deg[i0 + k]; }
    sh[t] = s; __syncthreads();
    for (int d = 128; d > 0; d >>= 1) { if (t < d) sh[t] += sh[t + d]; __syncthreads(); }
    if (t == 0) bsum[b] = sh[0];
}

// every block redundantly scans bsum (nb<=256), then emits its 1024 offsets
__global__ __launch_bounds__(256) void k_scan_out(const int* __restrict__ deg,
                                                  const int* __restrict__ bsum,
                                                  int* __restrict__ off, int nb, int n) {
    __shared__ int sb[256];
    __shared__ int sh[256];
    int b = blockIdx.x, t = threadIdx.x;
    int v = (t < nb) ? bsum[t] : 0;
    sb[t] = v; __syncthreads();
    for (int d = 1; d < 256; d <<= 1) {
        int u = (t >= d) ? sb[t - d] : 0;
        __syncthreads(); sb[t] += u; __syncthreads();
    }
    int base = (b == 0) ? 0 : sb[b - 1];
    if (b == 0 && t == 0) off[n] = sb[255];
    int i0 = b * 1024 + t * 4;
    int4 v4 = make_int4(0, 0, 0, 0);
    if (i0 + 3 < n) v4 = *(const int4*)(deg + i0);
    else {
        v4.x = (i0     < n) ? deg[i0]     : 0;
        v4.y = (i0 + 1 < n) ? deg[i0 + 1] : 0;
        v4.z = (i0 + 2 < n) ? deg[i0 + 2] : 0;
        v4.w = (i0 + 3 < n) ? deg[i0 + 3] : 0;
    }
    int s = v4.x + v4.y + v4.z + v4.w;
    sh[t] = s; __syncthreads();
    for (int d = 1; d < 256; d <<= 1) {
        int u = (t >= d) ? sh[t - d] : 0;
        __syncthreads(); sh[t] += u; __syncthreads();
    }
    int ex = base + sh[t] - s;
    if (i0     < n) off[i0]     = ex;
    if (i0 + 1 < n) off[i0 + 1] = ex + v4.x;
    if (i0 + 2 < n) off[i0 + 2] = ex + v4.x + v4.y;
    if (i0 + 3 < n) off[i0 + 3] = ex + v4.x + v4.y + v4.z;
}

// fused: blocks [0,nbE) build 16B fp16 edge records; blocks [nbE,..) do embed gather
__global__ void k_fill_embed(const int* __restrict__ src, const int* __restrict__ dst,
                             const float* __restrict__ eattr, const int* __restrict__ off,
                             const int* __restrict__ rank, uint4* __restrict__ rec, int E,
                             int nbE,
                             const int* __restrict__ x, const float* __restrict__ emb,
                             float* __restrict__ hcat, int N) {
    if ((int)blockIdx.x < nbE) {
        int e = blockIdx.x * 256 + threadIdx.x;
        if (e >= E) return;
        int slot = off[dst[e]] + rank[e];
        const float* ap = eattr + (size_t)e * 7;
        float a0 = ap[0], a1 = ap[1], a2 = ap[2], a3 = ap[3], a4 = ap[4], a5 = ap[5], a6 = ap[6];
        uint4 rv;
        h2 p01 = { (f16)a0, (f16)a1 };
        h2 p23 = { (f16)a2, (f16)a3 };
        h2 p45 = { (f16)a4, (f16)a5 };
        rv.x = __builtin_bit_cast(unsigned int, p01);
        rv.y = __builtin_bit_cast(unsigned int, p23);
        rv.z = __builtin_bit_cast(unsigned int, p45);
        unsigned int a6b = (unsigned int)__builtin_bit_cast(unsigned short, (f16)a6);
        rv.w = a6b | ((unsigned int)src[e] << 16);   // requires N < 65536
        rec[slot] = rv;
    } else {
        int idx = ((int)blockIdx.x - nbE) * 256 + threadIdx.x;
        int node = idx >> 4, j4 = (idx & 15) * 4;
        if (node < N) {
            float4 v = *(const float4*)(emb + (size_t)x[node] * 64 + j4);
            *(float4*)(hcat + (size_t)node * 256 + j4) = v;
        }
    }
}

// ---------------- tiled fp32 GEMM: [N,64]@[64,64] (+bias,relu); fp32 or fp16 out --
__global__ __launch_bounds__(256) void k_gemm64(
    const float* __restrict__ A, int a_stride,
    const float* __restrict__ B, const float* __restrict__ bias,
    float* __restrict__ C, int c_stride, f16* __restrict__ Ch,
    int N, int do_relu,
    const float* __restrict__ ar, float* __restrict__ r_out)
{
    __shared__ __align__(16) float sA[64][132];
    __shared__ __align__(16) float sB[64 * 64];
    __shared__ float sar[64];
    int tid = threadIdx.x;
    int row0 = blockIdx.x * 128;

    {
        const float4* b4 = (const float4*)B;
        float4* s4 = (float4*)sB;
        for (int i = tid; i < 1024; i += 256) s4[i] = b4[i];
    }
    if (ar && tid < 64) sar[tid] = ar[tid];

#pragma unroll
    for (int pass = 0; pass < 8; ++pass) {
        int nl = pass * 16 + (tid & 15);
        int k4 = (tid >> 4) * 4;
        int n = row0 + nl; if (n >= N) n = N - 1;
        float4 v = *(const float4*)(A + (size_t)n * a_stride + k4);
        sA[k4 + 0][nl] = v.x; sA[k4 + 1][nl] = v.y;
        sA[k4 + 2][nl] = v.z; sA[k4 + 3][nl] = v.w;
    }
    __syncthreads();

    int tr = tid >> 4, tc = tid & 15;
    int r0 = tr * 8, c0 = tc * 4;
    float acc[8][4];
#pragma unroll
    for (int i = 0; i < 8; i++)
#pragma unroll
        for (int j = 0; j < 4; j++) acc[i][j] = 0.f;

#pragma unroll 4
    for (int k = 0; k < 64; ++k) {
        float4 b4 = *(const float4*)(sB + k * 64 + c0);
        float4 a0 = *(const float4*)&sA[k][r0];
        float4 a1 = *(const float4*)&sA[k][r0 + 4];
#pragma unroll
        for (int j = 0; j < 4; j++) {
            float bj = (&b4.x)[j];
            acc[0][j] += a0.x * bj; acc[1][j] += a0.y * bj;
            acc[2][j] += a0.z * bj; acc[3][j] += a0.w * bj;
            acc[4][j] += a1.x * bj; acc[5][j] += a1.y * bj;
            acc[6][j] += a1.z * bj; acc[7][j] += a1.w * bj;
        }
    }

    float4 bv = make_float4(0.f, 0.f, 0.f, 0.f);
    if (bias) bv = *(const float4*)(bias + c0);
#pragma unroll
    for (int i = 0; i < 8; i++) {
        int n = row0 + r0 + i;
        if (n < N) {
            float4 o;
            o.x = acc[i][0] + bv.x; o.y = acc[i][1] + bv.y;
            o.z = acc[i][2] + bv.z; o.w = acc[i][3] + bv.w;
            if (do_relu) {
                o.x = fmaxf(o.x, 0.f); o.y = fmaxf(o.y, 0.f);
                o.z = fmaxf(o.z, 0.f); o.w = fmaxf(o.w, 0.f);
            }
            if (C) *(float4*)(C + (size_t)n * c_stride + c0) = o;
            if (Ch) {
                uint2 gw;
                gw.x = __builtin_bit_cast(unsigned int, __builtin_amdgcn_cvt_pkrtz(o.x, o.y));
                gw.y = __builtin_bit_cast(unsigned int, __builtin_amdgcn_cvt_pkrtz(o.z, o.w));
                *(uint2*)(Ch + (size_t)n * 64 + c0) = gw;
            }
        }
    }

    if (r_out && tid < 128) {
        int n = row0 + tid;
        if (n < N) {
            float racc = 0.f;
#pragma unroll
            for (int k = 0; k < 64; k++) racc += sA[k][tid] * sar[k];
            r_out[n] = racc;
        }
    }
}

// fused gemm2(layer l) + gemm1(layer l+1):
//   out1 = relu(agg@W2 + b) -> hc (in-place, stride 256)
//   g    = out1@W1n (fp16),  r = out1 . arn
__global__ __launch_bounds__(256) void k_gemm2g1(
    float* __restrict__ hc,
    const float* __restrict__ W2, const float* __restrict__ bias,
    const float* __restrict__ W1n, const float* __restrict__ arn,
    f16* __restrict__ g, float* __restrict__ r_out, int N)
{
    __shared__ __align__(16) float sA[64][132];
    __shared__ __align__(16) float sB[64 * 64];
    __shared__ float sar[64];
    int tid = threadIdx.x, row0 = blockIdx.x * 128;

    {
        const float4* b4 = (const float4*)W2;
        float4* s4 = (float4*)sB;
        for (int i = tid; i < 1024; i += 256) s4[i] = b4[i];
    }
    if (tid < 64) sar[tid] = arn[tid];

#pragma unroll
    for (int pass = 0; pass < 8; ++pass) {
        int nl = pass * 16 + (tid & 15);
        int k4 = (tid >> 4) * 4;
        int n = row0 + nl; if (n >= N) n = N - 1;
        float4 v = *(const float4*)(hc + (size_t)n * 256 + k4);
        sA[k4 + 0][nl] = v.x; sA[k4 + 1][nl] = v.y;
        sA[k4 + 2][nl] = v.z; sA[k4 + 3][nl] = v.w;
    }
    __syncthreads();

    int tr = tid >> 4, tc = tid & 15;
    int r0 = tr * 8, c0 = tc * 4;
    float acc[8][4];
#pragma unroll
    for (int i = 0; i < 8; i++)
#pragma unroll
        for (int j = 0; j < 4; j++) acc[i][j] = 0.f;

#pragma unroll 4
    for (int k = 0; k < 64; ++k) {
        float4 b4 = *(const float4*)(sB + k * 64 + c0);
        float4 a0 = *(const float4*)&sA[k][r0];
        float4 a1 = *(const float4*)&sA[k][r0 + 4];
#pragma unroll
        for (int j = 0; j < 4; j++) {
            float bj = (&b4.x)[j];
            acc[0][j] += a0.x * bj; acc[1][j] += a0.y * bj;
            acc[2][j] += a0.z * bj; acc[3][j] += a0.w * bj;
            acc[4][j] += a1.x * bj; acc[5][j] += a1.y * bj;
            acc[6][j] += a1.z * bj; acc[7][j] += a1.w * bj;
        }
    }

    float4 bv = *(const float4*)(bias + c0);
#pragma unroll
    for (int i = 0; i < 8; i++) {
        acc[i][0] = fmaxf(acc[i][0] + bv.x, 0.f);
        acc[i][1] = fmaxf(acc[i][1] + bv.y, 0.f);
        acc[i][2] = fmaxf(acc[i][2] + bv.z, 0.f);
        acc[i][3] = fmaxf(acc[i][3] + bv.w, 0.f);
        int n = row0 + r0 + i;
        if (n < N) *(float4*)(hc + (size_t)n * 256 + c0) =
            make_float4(acc[i][0], acc[i][1], acc[i][2], acc[i][3]);
    }
    __syncthreads();   // everyone done reading sA/sB

    // restage: sB <- W1n, sA <- out1^T
    {
        const float4* b4 = (const float4*)W1n;
        float4* s4 = (float4*)sB;
        for (int i = tid; i < 1024; i += 256) s4[i] = b4[i];
    }
#pragma unroll
    for (int i = 0; i < 8; i++)
#pragma unroll
        for (int j = 0; j < 4; j++) sA[c0 + j][r0 + i] = acc[i][j];
    __syncthreads();

#pragma unroll
    for (int i = 0; i < 8; i++)
#pragma unroll
        for (int j = 0; j < 4; j++) acc[i][j] = 0.f;

#pragma unroll 4
    for (int k = 0; k < 64; ++k) {
        float4 b4 = *(const float4*)(sB + k * 64 + c0);
        float4 a0 = *(const float4*)&sA[k][r0];
        float4 a1 = *(const float4*)&sA[k][r0 + 4];
#pragma unroll
        for (int j = 0; j < 4; j++) {
            float bj = (&b4.x)[j];
            acc[0][j] += a0.x * bj; acc[1][j] += a0.y * bj;
            acc[2][j] += a0.z * bj; acc[3][j] += a0.w * bj;
            acc[4][j] += a1.x * bj; acc[5][j] += a1.y * bj;
            acc[6][j] += a1.z * bj; acc[7][j] += a1.w * bj;
        }
    }

#pragma unroll
    for (int i = 0; i < 8; i++) {
        int n = row0 + r0 + i;
        if (n < N) {
            uint2 gw;
            gw.x = __builtin_bit_cast(unsigned int, __builtin_amdgcn_cvt_pkrtz(acc[i][0], acc[i][1]));
            gw.y = __builtin_bit_cast(unsigned int, __builtin_amdgcn_cvt_pkrtz(acc[i][2], acc[i][3]));
            *(uint2*)(g + (size_t)n * 64 + c0) = gw;
        }
    }
    if (tid < 128) {
        int n = row0 + tid;
        if (n < N) {
            float racc = 0.f;
#pragma unroll
            for (int k = 0; k < 64; k++) racc += sA[k][tid] * sar[k];
            r_out[n] = racc;
        }
    }
}

// ---------------- gate conv: wave/node, 16 edges/iter, fdot2 fp16 math ----
struct ConvW {
    h2 w01[4], w23[4], w45[4], w6_[4];
    h2 al01, al23;
};

__device__ __forceinline__ void edge_math(uint4 rv, uint2 gv, bool valid, float ri,
                                          const ConvW& W, float4& s, float& den) {
    h2 a01 = __builtin_bit_cast(h2, rv.x);
    h2 a23 = __builtin_bit_cast(h2, rv.y);
    h2 a45 = __builtin_bit_cast(h2, rv.z);
    h2 a6p = __builtin_bit_cast(h2, rv.w & 0xFFFFu);   // (a6, +0)
    h2 g01 = __builtin_bit_cast(h2, gv.x);
    h2 g23 = __builtin_bit_cast(h2, gv.y);

    float c0 = __builtin_amdgcn_fdot2(a01, W.w01[0],
               __builtin_amdgcn_fdot2(a23, W.w23[0],
               __builtin_amdgcn_fdot2(a45, W.w45[0],
               __builtin_amdgcn_fdot2(a6p, W.w6_[0], 0.f, false), false), false), false);
    float c1 = __builtin_amdgcn_fdot2(a01, W.w01[1],
               __builtin_amdgcn_fdot2(a23, W.w23[1],
               __builtin_amdgcn_fdot2(a45, W.w45[1],
               __builtin_amdgcn_fdot2(a6p, W.w6_[1], 0.f, false), false), false), false);
    float c2 = __builtin_amdgcn_fdot2(a01, W.w01[2],
               __builtin_amdgcn_fdot2(a23, W.w23[2],
               __builtin_amdgcn_fdot2(a45, W.w45[2],
               __builtin_amdgcn_fdot2(a6p, W.w6_[2], 0.f, false), false), false), false);
    float c3 = __builtin_amdgcn_fdot2(a01, W.w01[3],
               __builtin_amdgcn_fdot2(a23, W.w23[3],
               __builtin_amdgcn_fdot2(a45, W.w45[3],
               __builtin_amdgcn_fdot2(a6p, W.w6_[3], 0.f, false), false), false), false);

    h2 x01 = lrelu2(g01 + __builtin_amdgcn_cvt_pkrtz(c0, c1));
    h2 x23 = lrelu2(g23 + __builtin_amdgcn_cvt_pkrtz(c2, c3));
    float p = __builtin_amdgcn_fdot2(x01, W.al01,
              __builtin_amdgcn_fdot2(x23, W.al23, 0.f, false), false);
    p = q16_allsum(p);
    float alpha = lrelu(p + ri);
    float w = valid ? __expf(alpha) : 0.f;   // |alpha| bounded: no max-subtraction
    s.x += w * (float)x01.x; s.y += w * (float)x01.y;
    s.z += w * (float)x23.x; s.w += w * (float)x23.y;
    den += w;
}

__global__ __launch_bounds__(256) void k_conv(
    const int* __restrict__ off, const uint4* __restrict__ rec,
    const f16* __restrict__ g, const float* __restrict__ r,
    const uint4* __restrict__ wpack, float* __restrict__ aggdst, int N)
{
    int lane = threadIdx.x & 63;
    int wid  = threadIdx.x >> 6;
    int node = blockIdx.x * 4 + wid;
    if (node >= N) return;                 // wave-uniform exit, no barriers
    int q = lane >> 4, l16 = lane & 15;

    ConvW W;
    {
        const uint4* wp = wpack + l16 * 5;
        uint4 v0 = wp[0], v1 = wp[1], v2 = wp[2], v3 = wp[3], v4 = wp[4];
        W.w01[0] = __builtin_bit_cast(h2, v0.x); W.w01[1] = __builtin_bit_cast(h2, v0.y);
        W.w01[2] = __builtin_bit_cast(h2, v0.z); W.w01[3] = __builtin_bit_cast(h2, v0.w);
        W.w23[0] = __builtin_bit_cast(h2, v1.x); W.w23[1] = __builtin_bit_cast(h2, v1.y);
        W.w23[2] = __builtin_bit_cast(h2, v1.z); W.w23[3] = __builtin_bit_cast(h2, v1.w);
        W.w45[0] = __builtin_bit_cast(h2, v2.x); W.w45[1] = __builtin_bit_cast(h2, v2.y);
        W.w45[2] = __builtin_bit_cast(h2, v2.z); W.w45[3] = __builtin_bit_cast(h2, v2.w);
        W.w6_[0] = __builtin_bit_cast(h2, v3.x); W.w6_[1] = __builtin_bit_cast(h2, v3.y);
        W.w6_[2] = __builtin_bit_cast(h2, v3.z); W.w6_[3] = __builtin_bit_cast(h2, v3.w);
        W.al01   = __builtin_bit_cast(h2, v4.x); W.al23   = __builtin_bit_cast(h2, v4.y);
    }

    float ri = r[node];
    int e0 = off[node], e1 = off[node + 1];

    float4 s = make_float4(0.f, 0.f, 0.f, 0.f);
    float den = 0.f;
    for (int e = e0; e < e1; e += 16) {
        int ea = e + q, eb = ea + 4, ec = ea + 8, ed = ea + 12;
        int last = e1 - 1;
        bool va = ea < e1, vb = eb < e1, vc = ec < e1, vd = ed < e1;
        // issue all 4 record loads, then all 4 g-row gathers, before any math:
        // edge-a compute overlaps the b/c/d gather latency (in-order vmcnt).
        uint4 ra = rec[va ? ea : last];
        uint4 rb = rec[vb ? eb : last];
        uint4 rc = rec[vc ? ec : last];
        uint4 rd = rec[vd ? ed : last];
        uint2 ga = *(const uint2*)(g + (size_t)(ra.w >> 16) * 64 + 4 * l16);
        uint2 gb = *(const uint2*)(g + (size_t)(rb.w >> 16) * 64 + 4 * l16);
        uint2 gc = *(const uint2*)(g + (size_t)(rc.w >> 16) * 64 + 4 * l16);
        uint2 gd = *(const uint2*)(g + (size_t)(rd.w >> 16) * 64 + 4 * l16);
        edge_math(ra, ga, va, ri, W, s, den);
        edge_math(rb, gb, vb, ri, W, s, den);
        edge_math(rc, gc, vc, ri, W, s, den);
        edge_math(rd, gd, vd, ri, W, s, den);
    }
    s.x = x16_32_sum(s.x); s.y = x16_32_sum(s.y);
    s.z = x16_32_sum(s.z); s.w = x16_32_sum(s.w);
    den = x16_32_sum(den);
    float inv = 1.f / (den + 1e-16f);
    if (q == 0) {
        float4 o = make_float4(s.x * inv, s.y * inv, s.z * inv, s.w * inv);
        *(float4*)(aggdst + (size_t)node * 256 + 4 * l16) = o;
    }
}

// ---------------- fused final gemm2 (layer 2) + head ----------------
// h3 = relu(agg2@W2 + b) stays in LDS (never written to hcat);
// head: z = relu(hcat[:,0:192]·f1w + h3·f1w[192:] + f1b); out = sigmoid(z·f2w + f2b)
__global__ __launch_bounds__(256) void k_gemm2head(
    const float* __restrict__ hcat,
    const float* __restrict__ W2, const float* __restrict__ bias,
    const float* __restrict__ f1w, const float* __restrict__ f1b,
    const float* __restrict__ f2w, const float* __restrict__ f2b,
    float* __restrict__ out, int N)
{
    __shared__ __align__(16) float sA[64][132];   // gemm A staging, then sO[128][65]
    __shared__ __align__(16) float sBW[5120];     // W2 (4096), then f1w (5120)
    __shared__ float sP[128 * 20];                // partial z from upper half
    int tid = threadIdx.x, row0 = blockIdx.x * 128;

    {
        const float4* b4 = (const float4*)W2;
        float4* s4 = (float4*)sBW;
        for (int i = tid; i < 1024; i += 256) s4[i] = b4[i];
    }
#pragma unroll
    for (int pass = 0; pass < 8; ++pass) {
        int nl = pass * 16 + (tid & 15);
        int k4 = (tid >> 4) * 4;
        int n = row0 + nl; if (n >= N) n = N - 1;
        float4 v = *(const float4*)(hcat + (size_t)n * 256 + 192 + k4);
        sA[k4 + 0][nl] = v.x; sA[k4 + 1][nl] = v.y;
        sA[k4 + 2][nl] = v.z; sA[k4 + 3][nl] = v.w;
    }
    __syncthreads();

    int tr = tid >> 4, tc = tid & 15;
    int r0 = tr * 8, c0 = tc * 4;
    float acc[8][4];
#pragma unroll
    for (int i = 0; i < 8; i++)
#pragma unroll
        for (int j = 0; j < 4; j++) acc[i][j] = 0.f;

#pragma unroll 4
    for (int k = 0; k < 64; ++k) {
        float4 b4 = *(const float4*)(sBW + k * 64 + c0);
        float4 a0 = *(const float4*)&sA[k][r0];
        float4 a1 = *(const float4*)&sA[k][r0 + 4];
#pragma unroll
        for (int j = 0; j < 4; j++) {
            float bj = (&b4.x)[j];
            acc[0][j] += a0.x * bj; acc[1][j] += a0.y * bj;
            acc[2][j] += a0.z * bj; acc[3][j] += a0.w * bj;
            acc[4][j] += a1.x * bj; acc[5][j] += a1.y * bj;
            acc[6][j] += a1.z * bj; acc[7][j] += a1.w * bj;
        }
    }

    // issue f1w loads early (write to LDS only after the sync)
    float4 fw[5];
    {
        const float4* w4 = (const float4*)f1w;
#pragma unroll
        for (int i2 = 0; i2 < 5; i2++) fw[i2] = w4[tid + i2 * 256];
    }
    __syncthreads();   // everyone done reading sA/sBW

    float* sO = &sA[0][0];          // [128][65] = 8320 <= 8448 floats
    float4 bv = *(const float4*)(bias + c0);
#pragma unroll
    for (int i = 0; i < 8; i++) {
        acc[i][0] = fmaxf(acc[i][0] + bv.x, 0.f);
        acc[i][1] = fmaxf(acc[i][1] + bv.y, 0.f);
        acc[i][2] = fmaxf(acc[i][2] + bv.z, 0.f);
        acc[i][3] = fmaxf(acc[i][3] + bv.w, 0.f);
        int rr = r0 + i;
        sO[rr * 65 + c0 + 0] = acc[i][0];
        sO[rr * 65 + c0 + 1] = acc[i][1];
        sO[rr * 65 + c0 + 2] = acc[i][2];
        sO[rr * 65 + c0 + 3] = acc[i][3];
    }
    {
        float4* sw4 = (float4*)sBW;
#pragma unroll
        for (int i2 = 0; i2 < 5; i2++) sw4[tid + i2 * 256] = fw[i2];
    }
    __syncthreads();

    // head: 2 threads per row; half 0 -> k 0..127, half 1 -> k 128..255
    int rloc = tid & 127;
    int half = tid >> 7;
    int n = row0 + rloc;
    int nn = (n < N) ? n : N - 1;
    float z[20];
#pragma unroll
    for (int j = 0; j < 20; j++) z[j] = 0.f;
    const float4* hr = (const float4*)(hcat + (size_t)nn * 256);
    if (half == 0) {
        for (int k4 = 0; k4 < 32; k4++) {
            float4 h = hr[k4];
            const float* wr = sBW + k4 * 80;
#pragma unroll
            for (int j = 0; j < 20; j++)
                z[j] += h.x * wr[j] + h.y * wr[20 + j] + h.z * wr[40 + j] + h.w * wr[60 + j];
        }
    } else {
        for (int k4 = 32; k4 < 48; k4++) {
            float4 h = hr[k4];
            const float* wr = sBW + k4 * 80;
#pragma unroll
            for (int j = 0; j < 20; j++)
                z[j] += h.x * wr[j] + h.y * wr[20 + j] + h.z * wr[40 + j] + h.w * wr[60 + j];
        }
        for (int k = 0; k < 64; k += 2) {
            float hx = sO[rloc * 65 + k], hy = sO[rloc * 65 + k + 1];
            const float* wr = sBW + (192 + k) * 20;
#pragma unroll
            for (int j = 0; j < 20; j++)
                z[j] += hx * wr[j] + hy * wr[20 + j];
        }
#pragma unroll
        for (int j = 0; j < 20; j++) sP[rloc * 20 + j] = z[j];
    }
    __syncthreads();
    if (half == 0 && n < N) {
        float o = f2b[0];
#pragma unroll
        for (int j = 0; j < 20; j++) {
            float zj = z[j] + sP[rloc * 20 + j] + f1b[j];
            o += fmaxf(zj, 0.f) * f2w[j];
        }
        out[n] = 1.f / (1.f + __expf(-o));
    }
}

extern "C" void kernel_launch(void* const* d_in, const int* in_sizes, int n_in,
                              void* d_out, int out_size, void* d_ws, size_t ws_size,
                              hipStream_t stream) {
    const int*   x     = (const int*)d_in[0];
    const int*   eidx  = (const int*)d_in[1];
    const float* eattr = (const float*)d_in[2];
    const float* emb   = (const float*)d_in[3];
    const float* lin1  = (const float*)d_in[4];   // [3,71,64]
    const float* attl  = (const float*)d_in[5];   // [3,64]
    const float* attr_ = (const float*)d_in[6];   // [3,64]
    const float* lin2  = (const float*)d_in[7];   // [3,64,64]
    const float* gbias = (const float*)d_in[8];   // [3,64]
    const float* f1w   = (const float*)d_in[9];   // [256,20]
    const float* f1b   = (const float*)d_in[10];
    const float* f2w   = (const float*)d_in[11];
    const float* f2b   = (const float*)d_in[12];
    float* out = (float*)d_out;

    int N = in_sizes[0];
    int E = in_sizes[1] / 2;
    const int* src = eidx;
    const int* dst = eidx + E;

    // workspace carve (256B aligned) — ~83 MB
    char* p = (char*)d_ws;
    auto alloc = [&](size_t bytes) { void* q = (void*)p; p += (bytes + 255) & ~(size_t)255; return q; };
    float* hcat = (float*)alloc((size_t)N * 256 * 4);
    f16*   g    = (f16*)alloc((size_t)N * 64 * 2);
    float* r    = (float*)alloc((size_t)N * 4);
    int*   off  = (int*)alloc((size_t)(N + 1) * 4);
    int*   deg  = (int*)alloc((size_t)N * 4);
    int*   rank = (int*)alloc((size_t)E * 4);
    int*   bsum = (int*)alloc(256 * 4);
    uint4* rec  = (uint4*)alloc((size_t)E * 16);   // 16 B/edge: fp16 attrs + u16 src
    uint4* wpack = (uint4*)alloc((size_t)48 * 5 * 16);  // packed conv weights, 3 layers

    int nbs = (N + 1023) / 1024;     // 49 scan blocks (<=256)
    int nbE = (E + 255) / 256;
    int nbEmb = (N * 16 + 255) / 256;

    k_zero<<<(N + 255) / 256, 256, 0, stream>>>(deg, N, lin1, attl, wpack);
    k_count<<<nbE, 256, 0, stream>>>(dst, deg, rank, E);
    k_scan_part<<<nbs, 256, 0, stream>>>(deg, bsum, N);
    k_scan_out<<<nbs, 256, 0, stream>>>(deg, bsum, off, nbs, N);
    k_fill_embed<<<nbE + nbEmb, 256, 0, stream>>>(src, dst, eattr, off, rank, rec, E,
                                                  nbE, x, emb, hcat, N);

    int nbg = (N + 127) / 128;
    int nbc = (N + 3) / 4;
    // layer 0: g/r from embeddings
    k_gemm64<<<nbg, 256, 0, stream>>>(hcat, 256, lin1, nullptr,
                                      nullptr, 0, g, N, 0, attr_, r);
    k_conv<<<nbc, 256, 0, stream>>>(off, rec, g, r, wpack, hcat + 64, N);
    // layer boundary 0->1 and 1->2: fused gemm2 + gemm1(next)
    for (int l = 0; l < 2; l++) {
        k_gemm2g1<<<nbg, 256, 0, stream>>>(hcat + 64 * (l + 1),
                                           lin2 + (size_t)l * 4096, gbias + l * 64,
                                           lin1 + (size_t)(l + 1) * 71 * 64,
                                           attr_ + (l + 1) * 64, g, r, N);
        k_conv<<<nbc, 256, 0, stream>>>(off, rec, g, r,
                                        wpack + (size_t)(l + 1) * 80,
                                        hcat + 64 * (l + 2), N);
    }
    // fused final gemm2 (layer 2) + head: h3 never touches HBM
    k_gemm2head<<<nbg, 256, 0, stream>>>(hcat, lin2 + 2 * 4096, gbias + 128,
                                         f1w, f1b, f2w, f2b, out, N);
}

// Round 2
// 493.766 us; speedup vs baseline: 1.0783x; 1.0244x over previous
//
#include <hip/hip_runtime.h>
#include <math.h>

#define NEG 0.01f

typedef _Float16 f16;
typedef f16 h2 __attribute__((ext_vector_type(2)));

__device__ __forceinline__ float lrelu(float x) { return x > 0.f ? x : NEG * x; }

__device__ __forceinline__ h2 lrelu2(h2 x) {
    h2 y = x * (f16)0.01f;                        // v_pk_mul_f16
    return __builtin_elementwise_max(x, y);       // v_pk_max_f16 (x<0 -> 0.01x)
}

// sum across each 16-lane row via DPP; result in all 16 lanes of the row
__device__ __forceinline__ float q16_allsum(float v) {
    int x;
    x = __builtin_amdgcn_update_dpp(0, __float_as_int(v), 0xB1, 0xF, 0xF, true);  v += __int_as_float(x); // quad_perm xor1
    x = __builtin_amdgcn_update_dpp(0, __float_as_int(v), 0x4E, 0xF, 0xF, true);  v += __int_as_float(x); // quad_perm xor2
    x = __builtin_amdgcn_update_dpp(0, __float_as_int(v), 0x124, 0xF, 0xF, true); v += __int_as_float(x); // row_ror:4
    x = __builtin_amdgcn_update_dpp(0, __float_as_int(v), 0x128, 0xF, 0xF, true); v += __int_as_float(x); // row_ror:8
    return v;
}

__device__ __forceinline__ float x16_32_sum(float v) {
    v += __int_as_float(__builtin_amdgcn_ds_swizzle(__float_as_int(v), 0x401F)); // xor 16
    v += __shfl_xor(v, 32, 64);
    return v;
}

// ---------------- CSR build ----------------
// k_zero also packs the per-layer conv weights (fp16 ConvW layout) into ws:
// slot i in [0,48): layer l=i>>4, lane-slot t=i&15; 5 x uint4 per slot.
__global__ void k_zero(int* __restrict__ deg, int n,
                       const float* __restrict__ lin1, const float* __restrict__ attl,
                       uint4* __restrict__ wpack) {
    int i = blockIdx.x * blockDim.x + threadIdx.x;
    if (i < n) deg[i] = 0;
    if (i < 48) {
        int l = i >> 4, t = i & 15;
        const float* wb  = lin1 + (size_t)l * 71 * 64 + 64 * 64;  // rows 64..70
        const float* alp = attl + l * 64;
        unsigned int u[20];
#pragma unroll
        for (int j = 0; j < 4; j++) {
            int f = 4 * t + j;
            h2 a = { (f16)wb[f],       (f16)wb[64 + f]  }; u[j]      = __builtin_bit_cast(unsigned int, a);
            h2 b = { (f16)wb[128 + f], (f16)wb[192 + f] }; u[4 + j]  = __builtin_bit_cast(unsigned int, b);
            h2 c = { (f16)wb[256 + f], (f16)wb[320 + f] }; u[8 + j]  = __builtin_bit_cast(unsigned int, c);
            h2 d = { (f16)wb[384 + f], (f16)0.f         }; u[12 + j] = __builtin_bit_cast(unsigned int, d);
        }
        h2 e0 = { (f16)alp[4 * t],     (f16)alp[4 * t + 1] }; u[16] = __builtin_bit_cast(unsigned int, e0);
        h2 e1 = { (f16)alp[4 * t + 2], (f16)alp[4 * t + 3] }; u[17] = __builtin_bit_cast(unsigned int, e1);
        u[18] = 0; u[19] = 0;
        uint4* o = wpack + (size_t)i * 5;
        o[0] = make_uint4(u[0],  u[1],  u[2],  u[3]);
        o[1] = make_uint4(u[4],  u[5],  u[6],  u[7]);
        o[2] = make_uint4(u[8],  u[9],  u[10], u[11]);
        o[3] = make_uint4(u[12], u[13], u[14], u[15]);
        o[4] = make_uint4(u[16], u[17], u[18], u[19]);
    }
}

// fused: blocks [0,nbCnt) do edge-degree count; blocks [nbCnt,..) do the
// layer-0 gemm (g = emb[x]@W1a, r = emb[x].ar) -- independent of CSR state,
// A gathered directly from the embedding table (64-row tiles, 3 blocks/CU).
__global__ __launch_bounds__(256) void k_count_gemm(
    const int* __restrict__ dst, int* __restrict__ deg, int* __restrict__ rank,
    int E, int nbCnt,
    const int* __restrict__ x, const float* __restrict__ emb,
    const float* __restrict__ B, const float* __restrict__ ar,
    f16* __restrict__ g, float* __restrict__ r_out, int N)
{
    __shared__ __align__(16) float sA[64][68];
    __shared__ __align__(16) float sB[64 * 64];
    __shared__ float sar[64];
    if ((int)blockIdx.x < nbCnt) {
        int e = blockIdx.x * 256 + threadIdx.x;
        if (e < E) rank[e] = atomicAdd(&deg[dst[e]], 1);
        return;
    }
    int tid = threadIdx.x;
    int row0 = ((int)blockIdx.x - nbCnt) * 64;

    {
        const float4* b4 = (const float4*)B;
        float4* s4 = (float4*)sB;
        for (int i = tid; i < 1024; i += 256) s4[i] = b4[i];
    }
    if (tid < 64) sar[tid] = ar[tid];

#pragma unroll
    for (int pass = 0; pass < 4; ++pass) {
        int nl = pass * 16 + (tid & 15);
        int k4 = (tid >> 4) * 4;
        int n = row0 + nl; if (n >= N) n = N - 1;
        float4 v = *(const float4*)(emb + (size_t)x[n] * 64 + k4);
        sA[k4 + 0][nl] = v.x; sA[k4 + 1][nl] = v.y;
        sA[k4 + 2][nl] = v.z; sA[k4 + 3][nl] = v.w;
    }
    __syncthreads();

    int tr = tid >> 4, tc = tid & 15;
    int r0 = tr * 4, c0 = tc * 4;
    float acc[4][4];
#pragma unroll
    for (int i = 0; i < 4; i++)
#pragma unroll
        for (int j = 0; j < 4; j++) acc[i][j] = 0.f;

#pragma unroll 4
    for (int k = 0; k < 64; ++k) {
        float4 b4 = *(const float4*)(sB + k * 64 + c0);
        float4 a0 = *(const float4*)&sA[k][r0];
#pragma unroll
        for (int j = 0; j < 4; j++) {
            float bj = (&b4.x)[j];
            acc[0][j] += a0.x * bj; acc[1][j] += a0.y * bj;
            acc[2][j] += a0.z * bj; acc[3][j] += a0.w * bj;
        }
    }

#pragma unroll
    for (int i = 0; i < 4; i++) {
        int n = row0 + r0 + i;
        if (n < N) {
            uint2 gw;
            gw.x = __builtin_bit_cast(unsigned int, __builtin_amdgcn_cvt_pkrtz(acc[i][0], acc[i][1]));
            gw.y = __builtin_bit_cast(unsigned int, __builtin_amdgcn_cvt_pkrtz(acc[i][2], acc[i][3]));
            *(uint2*)(g + (size_t)n * 64 + c0) = gw;
        }
    }
    if (tid < 64) {
        int n = row0 + tid;
        if (n < N) {
            float racc = 0.f;
#pragma unroll
            for (int k = 0; k < 64; k++) racc += sA[k][tid] * sar[k];
            r_out[n] = racc;
        }
    }
}

__global__ __launch_bounds__(256) void k_scan_part(const int* __restrict__ deg,
                                                   int* __restrict__ bsum, int n) {
    __shared__ int sh[256];
    int b = blockIdx.x, t = threadIdx.x;
    int i0 = b * 1024 + t * 4;
    int s = 0;
    if (i0 + 3 < n) { int4 v = *(const int4*)(deg + i0); s = v.x + v.y + v.z + v.w; }
    else { for (int k = 0; k < 4; k++) if (i0 + k < n) s += deg[i0 + k]; }
    sh[t] = s; __syncthreads();
    for (int d = 128; d > 0; d >>= 1) { if (t < d) sh[t] += sh[t + d]; __syncthreads(); }
    if (t == 0) bsum[b] = sh[0];
}

// every block redundantly scans bsum (nb<=256), then emits its 1024 offsets
__global__ __launch_bounds__(256) void k_scan_out(const int* __restrict__ deg,
                                                  const int* __restrict__ bsum,
                                                  int* __restrict__ off, int nb, int n) {
    __shared__ int sb[256];
    __shared__ int sh[256];
    int b = blockIdx.x, t = threadIdx.x;
    int v = (t < nb) ? bsum[t] : 0;
    sb[t] = v; __syncthreads();
    for (int d = 1; d < 256; d <<= 1) {
        int u = (t >= d) ? sb[t - d] : 0;
        __syncthreads(); sb[t] += u; __syncthreads();
    }
    int base = (b == 0) ? 0 : sb[b - 1];
    if (b == 0 && t == 0) off[n] = sb[255];
    int i0 = b * 1024 + t * 4;
    int4 v4 = make_int4(0, 0, 0, 0);
    if (i0 + 3 < n) v4 = *(const int4*)(deg + i0);
    else {
        v4.x = (i0     < n) ? deg[i0]     : 0;
        v4.y = (i0 + 1 < n) ? deg[i0 + 1] : 0;
        v4.z = (i0 + 2 < n) ? deg[i0 + 2] : 0;
        v4.w = (i0 + 3 < n) ? deg[i0 + 3] : 0;
    }
    int s = v4.x + v4.y + v4.z + v4.w;
    sh[t] = s; __syncthreads();
    for (int d = 1; d < 256; d <<= 1) {
        int u = (t >= d) ? sh[t - d] : 0;
        __syncthreads(); sh[t] += u; __syncthreads();
    }
    int ex = base + sh[t] - s;
    if (i0     < n) off[i0]     = ex;
    if (i0 + 1 < n) off[i0 + 1] = ex + v4.x;
    if (i0 + 2 < n) off[i0 + 2] = ex + v4.x + v4.y;
    if (i0 + 3 < n) off[i0 + 3] = ex + v4.x + v4.y + v4.z;
}

// fused: blocks [0,nbE) build 16B fp16 edge records; blocks [nbE,..) do embed gather
__global__ void k_fill_embed(const int* __restrict__ src, const int* __restrict__ dst,
                             const float* __restrict__ eattr, const int* __restrict__ off,
                             const int* __restrict__ rank, uint4* __restrict__ rec, int E,
                             int nbE,
                             const int* __restrict__ x, const float* __restrict__ emb,
                             float* __restrict__ hcat, int N) {
    if ((int)blockIdx.x < nbE) {
        int e = blockIdx.x * 256 + threadIdx.x;
        if (e >= E) return;
        int slot = off[dst[e]] + rank[e];
        const float* ap = eattr + (size_t)e * 7;
        float a0 = ap[0], a1 = ap[1], a2 = ap[2], a3 = ap[3], a4 = ap[4], a5 = ap[5], a6 = ap[6];
        uint4 rv;
        h2 p01 = { (f16)a0, (f16)a1 };
        h2 p23 = { (f16)a2, (f16)a3 };
        h2 p45 = { (f16)a4, (f16)a5 };
        rv.x = __builtin_bit_cast(unsigned int, p01);
        rv.y = __builtin_bit_cast(unsigned int, p23);
        rv.z = __builtin_bit_cast(unsigned int, p45);
        unsigned int a6b = (unsigned int)__builtin_bit_cast(unsigned short, (f16)a6);
        rv.w = a6b | ((unsigned int)src[e] << 16);   // requires N < 65536
        rec[slot] = rv;
    } else {
        int idx = ((int)blockIdx.x - nbE) * 256 + threadIdx.x;
        int node = idx >> 4, j4 = (idx & 15) * 4;
        if (node < N) {
            float4 v = *(const float4*)(emb + (size_t)x[node] * 64 + j4);
            *(float4*)(hcat + (size_t)node * 256 + j4) = v;
        }
    }
}

// fused gemm2(layer l) + gemm1(layer l+1), 64-row tiles:
//   out1 = relu(agg@W2 + b) -> hc (in-place, stride 256)
//   g    = out1@W1n (fp16),  r = out1 . arn
__global__ __launch_bounds__(256) void k_gemm2g1(
    float* __restrict__ hc,
    const float* __restrict__ W2, const float* __restrict__ bias,
    const float* __restrict__ W1n, const float* __restrict__ arn,
    f16* __restrict__ g, float* __restrict__ r_out, int N)
{
    __shared__ __align__(16) float sA[64][68];
    __shared__ __align__(16) float sB[64 * 64];
    __shared__ float sar[64];
    int tid = threadIdx.x, row0 = blockIdx.x * 64;

    {
        const float4* b4 = (const float4*)W2;
        float4* s4 = (float4*)sB;
        for (int i = tid; i < 1024; i += 256) s4[i] = b4[i];
    }
    if (tid < 64) sar[tid] = arn[tid];

#pragma unroll
    for (int pass = 0; pass < 4; ++pass) {
        int nl = pass * 16 + (tid & 15);
        int k4 = (tid >> 4) * 4;
        int n = row0 + nl; if (n >= N) n = N - 1;
        float4 v = *(const float4*)(hc + (size_t)n * 256 + k4);
        sA[k4 + 0][nl] = v.x; sA[k4 + 1][nl] = v.y;
        sA[k4 + 2][nl] = v.z; sA[k4 + 3][nl] = v.w;
    }
    __syncthreads();

    int tr = tid >> 4, tc = tid & 15;
    int r0 = tr * 4, c0 = tc * 4;
    float acc[4][4];
#pragma unroll
    for (int i = 0; i < 4; i++)
#pragma unroll
        for (int j = 0; j < 4; j++) acc[i][j] = 0.f;

#pragma unroll 4
    for (int k = 0; k < 64; ++k) {
        float4 b4 = *(const float4*)(sB + k * 64 + c0);
        float4 a0 = *(const float4*)&sA[k][r0];
#pragma unroll
        for (int j = 0; j < 4; j++) {
            float bj = (&b4.x)[j];
            acc[0][j] += a0.x * bj; acc[1][j] += a0.y * bj;
            acc[2][j] += a0.z * bj; acc[3][j] += a0.w * bj;
        }
    }

    float4 bv = *(const float4*)(bias + c0);
#pragma unroll
    for (int i = 0; i < 4; i++) {
        acc[i][0] = fmaxf(acc[i][0] + bv.x, 0.f);
        acc[i][1] = fmaxf(acc[i][1] + bv.y, 0.f);
        acc[i][2] = fmaxf(acc[i][2] + bv.z, 0.f);
        acc[i][3] = fmaxf(acc[i][3] + bv.w, 0.f);
        int n = row0 + r0 + i;
        if (n < N) *(float4*)(hc + (size_t)n * 256 + c0) =
            make_float4(acc[i][0], acc[i][1], acc[i][2], acc[i][3]);
    }
    __syncthreads();   // everyone done reading sA/sB

    // restage: sB <- W1n, sA <- out1^T
    {
        const float4* b4 = (const float4*)W1n;
        float4* s4 = (float4*)sB;
        for (int i = tid; i < 1024; i += 256) s4[i] = b4[i];
    }
#pragma unroll
    for (int i = 0; i < 4; i++)
#pragma unroll
        for (int j = 0; j < 4; j++) sA[c0 + j][r0 + i] = acc[i][j];
    __syncthreads();

#pragma unroll
    for (int i = 0; i < 4; i++)
#pragma unroll
        for (int j = 0; j < 4; j++) acc[i][j] = 0.f;

#pragma unroll 4
    for (int k = 0; k < 64; ++k) {
        float4 b4 = *(const float4*)(sB + k * 64 + c0);
        float4 a0 = *(const float4*)&sA[k][r0];
#pragma unroll
        for (int j = 0; j < 4; j++) {
            float bj = (&b4.x)[j];
            acc[0][j] += a0.x * bj; acc[1][j] += a0.y * bj;
            acc[2][j] += a0.z * bj; acc[3][j] += a0.w * bj;
        }
    }

#pragma unroll
    for (int i = 0; i < 4; i++) {
        int n = row0 + r0 + i;
        if (n < N) {
            uint2 gw;
            gw.x = __builtin_bit_cast(unsigned int, __builtin_amdgcn_cvt_pkrtz(acc[i][0], acc[i][1]));
            gw.y = __builtin_bit_cast(unsigned int, __builtin_amdgcn_cvt_pkrtz(acc[i][2], acc[i][3]));
            *(uint2*)(g + (size_t)n * 64 + c0) = gw;
        }
    }
    if (tid < 64) {
        int n = row0 + tid;
        if (n < N) {
            float racc = 0.f;
#pragma unroll
            for (int k = 0; k < 64; k++) racc += sA[k][tid] * sar[k];
            r_out[n] = racc;
        }
    }
}

// ---------------- gate conv: wave/node, 16 edges/iter, 2-stage pipeline ----
struct ConvW {
    h2 w01[4], w23[4], w45[4], w6_[4];
    h2 al01, al23;
};

__device__ __forceinline__ void edge_math(uint4 rv, uint2 gv, bool valid, float ri,
                                          const ConvW& W, float4& s, float& den) {
    h2 a01 = __builtin_bit_cast(h2, rv.x);
    h2 a23 = __builtin_bit_cast(h2, rv.y);
    h2 a45 = __builtin_bit_cast(h2, rv.z);
    h2 a6p = __builtin_bit_cast(h2, rv.w & 0xFFFFu);   // (a6, +0)
    h2 g01 = __builtin_bit_cast(h2, gv.x);
    h2 g23 = __builtin_bit_cast(h2, gv.y);

    float c0 = __builtin_amdgcn_fdot2(a01, W.w01[0],
               __builtin_amdgcn_fdot2(a23, W.w23[0],
               __builtin_amdgcn_fdot2(a45, W.w45[0],
               __builtin_amdgcn_fdot2(a6p, W.w6_[0], 0.f, false), false), false), false);
    float c1 = __builtin_amdgcn_fdot2(a01, W.w01[1],
               __builtin_amdgcn_fdot2(a23, W.w23[1],
               __builtin_amdgcn_fdot2(a45, W.w45[1],
               __builtin_amdgcn_fdot2(a6p, W.w6_[1], 0.f, false), false), false), false);
    float c2 = __builtin_amdgcn_fdot2(a01, W.w01[2],
               __builtin_amdgcn_fdot2(a23, W.w23[2],
               __builtin_amdgcn_fdot2(a45, W.w45[2],
               __builtin_amdgcn_fdot2(a6p, W.w6_[2], 0.f, false), false), false), false);
    float c3 = __builtin_amdgcn_fdot2(a01, W.w01[3],
               __builtin_amdgcn_fdot2(a23, W.w23[3],
               __builtin_amdgcn_fdot2(a45, W.w45[3],
               __builtin_amdgcn_fdot2(a6p, W.w6_[3], 0.f, false), false), false), false);

    h2 x01 = lrelu2(g01 + __builtin_amdgcn_cvt_pkrtz(c0, c1));
    h2 x23 = lrelu2(g23 + __builtin_amdgcn_cvt_pkrtz(c2, c3));
    float p = __builtin_amdgcn_fdot2(x01, W.al01,
              __builtin_amdgcn_fdot2(x23, W.al23, 0.f, false), false);
    p = q16_allsum(p);
    float alpha = lrelu(p + ri);
    float w = valid ? __expf(alpha) : 0.f;   // |alpha| bounded: no max-subtraction
    s.x += w * (float)x01.x; s.y += w * (float)x01.y;
    s.z += w * (float)x23.x; s.w += w * (float)x23.y;
    den += w;
}

__global__ __launch_bounds__(256) void k_conv(
    const int* __restrict__ off, const uint4* __restrict__ rec,
    const f16* __restrict__ g, const float* __restrict__ r,
    const uint4* __restrict__ wpack, float* __restrict__ aggdst, int N)
{
    int lane = threadIdx.x & 63;
    int wid  = threadIdx.x >> 6;
    int node = blockIdx.x * 4 + wid;
    if (node >= N) return;                 // wave-uniform exit, no barriers
    int q = lane >> 4, l16 = lane & 15;

    ConvW W;
    {
        const uint4* wp = wpack + l16 * 5;
        uint4 v0 = wp[0], v1 = wp[1], v2 = wp[2], v3 = wp[3], v4 = wp[4];
        W.w01[0] = __builtin_bit_cast(h2, v0.x); W.w01[1] = __builtin_bit_cast(h2, v0.y);
        W.w01[2] = __builtin_bit_cast(h2, v0.z); W.w01[3] = __builtin_bit_cast(h2, v0.w);
        W.w23[0] = __builtin_bit_cast(h2, v1.x); W.w23[1] = __builtin_bit_cast(h2, v1.y);
        W.w23[2] = __builtin_bit_cast(h2, v1.z); W.w23[3] = __builtin_bit_cast(h2, v1.w);
        W.w45[0] = __builtin_bit_cast(h2, v2.x); W.w45[1] = __builtin_bit_cast(h2, v2.y);
        W.w45[2] = __builtin_bit_cast(h2, v2.z); W.w45[3] = __builtin_bit_cast(h2, v2.w);
        W.w6_[0] = __builtin_bit_cast(h2, v3.x); W.w6_[1] = __builtin_bit_cast(h2, v3.y);
        W.w6_[2] = __builtin_bit_cast(h2, v3.z); W.w6_[3] = __builtin_bit_cast(h2, v3.w);
        W.al01   = __builtin_bit_cast(h2, v4.x); W.al23   = __builtin_bit_cast(h2, v4.y);
    }

    float ri = r[node];
    int e0 = off[node], e1 = off[node + 1];

    float4 s = make_float4(0.f, 0.f, 0.f, 0.f);
    float den = 0.f;
    if (e0 < e1) {
        int last = e1 - 1;
        // prologue: records for the first 16-edge group
        int ea = e0 + q, eb = ea + 4, ec = ea + 8, ed = ea + 12;
        uint4 ra = rec[ea < e1 ? ea : last];
        uint4 rb = rec[eb < e1 ? eb : last];
        uint4 rc = rec[ec < e1 ? ec : last];
        uint4 rd = rec[ed < e1 ? ed : last];
        for (int e = e0; e < e1; e += 16) {
            // issue current g-gathers (recs already resident from prev iter)
            uint2 ga = *(const uint2*)(g + (size_t)(ra.w >> 16) * 64 + 4 * l16);
            uint2 gb = *(const uint2*)(g + (size_t)(rb.w >> 16) * 64 + 4 * l16);
            uint2 gc = *(const uint2*)(g + (size_t)(rc.w >> 16) * 64 + 4 * l16);
            uint2 gd = *(const uint2*)(g + (size_t)(rd.w >> 16) * 64 + 4 * l16);
            // prefetch next iteration's records (clamped, always safe)
            int en = e + 16;
            int fa = en + q, fb = fa + 4, fc = fa + 8, fd = fa + 12;
            uint4 na = rec[fa < e1 ? fa : last];
            uint4 nb = rec[fb < e1 ? fb : last];
            uint4 nc = rec[fc < e1 ? fc : last];
            uint4 nd = rec[fd < e1 ? fd : last];
            bool va = (e + q)      < e1, vb = (e + 4 + q)  < e1;
            bool vc = (e + 8 + q)  < e1, vd = (e + 12 + q) < e1;
            edge_math(ra, ga, va, ri, W, s, den);
            edge_math(rb, gb, vb, ri, W, s, den);
            edge_math(rc, gc, vc, ri, W, s, den);
            edge_math(rd, gd, vd, ri, W, s, den);
            ra = na; rb = nb; rc = nc; rd = nd;
        }
    }
    s.x = x16_32_sum(s.x); s.y = x16_32_sum(s.y);
    s.z = x16_32_sum(s.z); s.w = x16_32_sum(s.w);
    den = x16_32_sum(den);
    float inv = 1.f / (den + 1e-16f);
    if (q == 0) {
        float4 o = make_float4(s.x * inv, s.y * inv, s.z * inv, s.w * inv);
        *(float4*)(aggdst + (size_t)node * 256 + 4 * l16) = o;
    }
}

// ---------------- fused final gemm2 (layer 2) + head ----------------
// h3 = relu(agg2@W2 + b) stays in LDS (never written to hcat);
// head: z = relu(hcat[:,0:192]·f1w + h3·f1w[192:] + f1b); out = sigmoid(z·f2w + f2b)
__global__ __launch_bounds__(256) void k_gemm2head(
    const float* __restrict__ hcat,
    const float* __restrict__ W2, const float* __restrict__ bias,
    const float* __restrict__ f1w, const float* __restrict__ f1b,
    const float* __restrict__ f2w, const float* __restrict__ f2b,
    float* __restrict__ out, int N)
{
    __shared__ __align__(16) float sA[64][132];   // gemm A staging, then sO[128][65]
    __shared__ __align__(16) float sBW[5120];     // W2 (4096), then f1w (5120)
    __shared__ float sP[128 * 20];                // partial z from upper half
    int tid = threadIdx.x, row0 = blockIdx.x * 128;

    {
        const float4* b4 = (const float4*)W2;
        float4* s4 = (float4*)sBW;
        for (int i = tid; i < 1024; i += 256) s4[i] = b4[i];
    }
#pragma unroll
    for (int pass = 0; pass < 8; ++pass) {
        int nl = pass * 16 + (tid & 15);
        int k4 = (tid >> 4) * 4;
        int n = row0 + nl; if (n >= N) n = N - 1;
        float4 v = *(const float4*)(hcat + (size_t)n * 256 + 192 + k4);
        sA[k4 + 0][nl] = v.x; sA[k4 + 1][nl] = v.y;
        sA[k4 + 2][nl] = v.z; sA[k4 + 3][nl] = v.w;
    }
    __syncthreads();

    int tr = tid >> 4, tc = tid & 15;
    int r0 = tr * 8, c0 = tc * 4;
    float acc[8][4];
#pragma unroll
    for (int i = 0; i < 8; i++)
#pragma unroll
        for (int j = 0; j < 4; j++) acc[i][j] = 0.f;

#pragma unroll 4
    for (int k = 0; k < 64; ++k) {
        float4 b4 = *(const float4*)(sBW + k * 64 + c0);
        float4 a0 = *(const float4*)&sA[k][r0];
        float4 a1 = *(const float4*)&sA[k][r0 + 4];
#pragma unroll
        for (int j = 0; j < 4; j++) {
            float bj = (&b4.x)[j];
            acc[0][j] += a0.x * bj; acc[1][j] += a0.y * bj;
            acc[2][j] += a0.z * bj; acc[3][j] += a0.w * bj;
            acc[4][j] += a1.x * bj; acc[5][j] += a1.y * bj;
            acc[6][j] += a1.z * bj; acc[7][j] += a1.w * bj;
        }
    }

    // issue f1w loads early (write to LDS only after the sync)
    float4 fw[5];
    {
        const float4* w4 = (const float4*)f1w;
#pragma unroll
        for (int i2 = 0; i2 < 5; i2++) fw[i2] = w4[tid + i2 * 256];
    }
    __syncthreads();   // everyone done reading sA/sBW

    float* sO = &sA[0][0];          // [128][65] = 8320 <= 8448 floats
    float4 bv = *(const float4*)(bias + c0);
#pragma unroll
    for (int i = 0; i < 8; i++) {
        acc[i][0] = fmaxf(acc[i][0] + bv.x, 0.f);
        acc[i][1] = fmaxf(acc[i][1] + bv.y, 0.f);
        acc[i][2] = fmaxf(acc[i][2] + bv.z, 0.f);
        acc[i][3] = fmaxf(acc[i][3] + bv.w, 0.f);
        int rr = r0 + i;
        sO[rr * 65 + c0 + 0] = acc[i][0];
        sO[rr * 65 + c0 + 1] = acc[i][1];
        sO[rr * 65 + c0 + 2] = acc[i][2];
        sO[rr * 65 + c0 + 3] = acc[i][3];
    }
    {
        float4* sw4 = (float4*)sBW;
#pragma unroll
        for (int i2 = 0; i2 < 5; i2++) sw4[tid + i2 * 256] = fw[i2];
    }
    __syncthreads();

    // head: 2 threads per row; half 0 -> k 0..127, half 1 -> k 128..255
    int rloc = tid & 127;
    int half = tid >> 7;
    int n = row0 + rloc;
    int nn = (n < N) ? n : N - 1;
    float z[20];
#pragma unroll
    for (int j = 0; j < 20; j++) z[j] = 0.f;
    const float4* hr = (const float4*)(hcat + (size_t)nn * 256);
    if (half == 0) {
        for (int k4 = 0; k4 < 32; k4++) {
            float4 h = hr[k4];
            const float* wr = sBW + k4 * 80;
#pragma unroll
            for (int j = 0; j < 20; j++)
                z[j] += h.x * wr[j] + h.y * wr[20 + j] + h.z * wr[40 + j] + h.w * wr[60 + j];
        }
    } else {
        for (int k4 = 32; k4 < 48; k4++) {
            float4 h = hr[k4];
            const float* wr = sBW + k4 * 80;
#pragma unroll
            for (int j = 0; j < 20; j++)
                z[j] += h.x * wr[j] + h.y * wr[20 + j] + h.z * wr[40 + j] + h.w * wr[60 + j];
        }
        for (int k = 0; k < 64; k += 2) {
            float hx = sO[rloc * 65 + k], hy = sO[rloc * 65 + k + 1];
            const float* wr = sBW + (192 + k) * 20;
#pragma unroll
            for (int j = 0; j < 20; j++)
                z[j] += hx * wr[j] + hy * wr[20 + j];
        }
#pragma unroll
        for (int j = 0; j < 20; j++) sP[rloc * 20 + j] = z[j];
    }
    __syncthreads();
    if (half == 0 && n < N) {
        float o = f2b[0];
#pragma unroll
        for (int j = 0; j < 20; j++) {
            float zj = z[j] + sP[rloc * 20 + j] + f1b[j];
            o += fmaxf(zj, 0.f) * f2w[j];
        }
        out[n] = 1.f / (1.f + __expf(-o));
    }
}

extern "C" void kernel_launch(void* const* d_in, const int* in_sizes, int n_in,
                              void* d_out, int out_size, void* d_ws, size_t ws_size,
                              hipStream_t stream) {
    const int*   x     = (const int*)d_in[0];
    const int*   eidx  = (const int*)d_in[1];
    const float* eattr = (const float*)d_in[2];
    const float* emb   = (const float*)d_in[3];
    const float* lin1  = (const float*)d_in[4];   // [3,71,64]
    const float* attl  = (const float*)d_in[5];   // [3,64]
    const float* attr_ = (const float*)d_in[6];   // [3,64]
    const float* lin2  = (const float*)d_in[7];   // [3,64,64]
    const float* gbias = (const float*)d_in[8];   // [3,64]
    const float* f1w   = (const float*)d_in[9];   // [256,20]
    const float* f1b   = (const float*)d_in[10];
    const float* f2w   = (const float*)d_in[11];
    const float* f2b   = (const float*)d_in[12];
    float* out = (float*)d_out;

    int N = in_sizes[0];
    int E = in_sizes[1] / 2;
    const int* src = eidx;
    const int* dst = eidx + E;

    // workspace carve (256B aligned) — ~83 MB
    char* p = (char*)d_ws;
    auto alloc = [&](size_t bytes) { void* q = (void*)p; p += (bytes + 255) & ~(size_t)255; return q; };
    float* hcat = (float*)alloc((size_t)N * 256 * 4);
    f16*   g    = (f16*)alloc((size_t)N * 64 * 2);
    float* r    = (float*)alloc((size_t)N * 4);
    int*   off  = (int*)alloc((size_t)(N + 1) * 4);
    int*   deg  = (int*)alloc((size_t)N * 4);
    int*   rank = (int*)alloc((size_t)E * 4);
    int*   bsum = (int*)alloc(256 * 4);
    uint4* rec  = (uint4*)alloc((size_t)E * 16);   // 16 B/edge: fp16 attrs + u16 src
    uint4* wpack = (uint4*)alloc((size_t)48 * 5 * 16);  // packed conv weights, 3 layers

    int nbs   = (N + 1023) / 1024;   // 49 scan blocks (<=256)
    int nbE   = (E + 255) / 256;
    int nbEmb = (N * 16 + 255) / 256;
    int nbg64 = (N + 63) / 64;       // 782 gemm tiles
    int nbg128 = (N + 127) / 128;
    int nbc   = (N + 3) / 4;

    k_zero<<<(N + 255) / 256, 256, 0, stream>>>(deg, N, lin1, attl, wpack);
    // CSR count overlapped with layer-0 gemm (independent: A gathered from emb)
    k_count_gemm<<<nbE + nbg64, 256, 0, stream>>>(dst, deg, rank, E, nbE,
                                                  x, emb, lin1, attr_, g, r, N);
    k_scan_part<<<nbs, 256, 0, stream>>>(deg, bsum, N);
    k_scan_out<<<nbs, 256, 0, stream>>>(deg, bsum, off, nbs, N);
    k_fill_embed<<<nbE + nbEmb, 256, 0, stream>>>(src, dst, eattr, off, rank, rec, E,
                                                  nbE, x, emb, hcat, N);

    k_conv<<<nbc, 256, 0, stream>>>(off, rec, g, r, wpack, hcat + 64, N);
    for (int l = 0; l < 2; l++) {
        k_gemm2g1<<<nbg64, 256, 0, stream>>>(hcat + 64 * (l + 1),
                                             lin2 + (size_t)l * 4096, gbias + l * 64,
                                             lin1 + (size_t)(l + 1) * 71 * 64,
                                             attr_ + (l + 1) * 64, g, r, N);
        k_conv<<<nbc, 256, 0, stream>>>(off, rec, g, r,
                                        wpack + (size_t)(l + 1) * 80,
                                        hcat + 64 * (l + 2), N);
    }
    // fused final gemm2 (layer 2) + head: h3 never touches HBM
    k_gemm2head<<<nbg128, 256, 0, stream>>>(hcat, lin2 + 2 * 4096, gbias + 128,
                                            f1w, f1b, f2w, f2b, out, N);
}